// Round 1
// baseline (870.509 us; speedup 1.0000x reference)
//
#include <hip/hip_runtime.h>

#define NF 64
#define NH 32
#define NK 16
#define NNODES 15
#define BLOCK 640
#define NWAVES (BLOCK / 64)

// LDS: subL 960 + permL 2560 + sortL 320 = ~3.8 KB (was 65 KB).
// Weights are delivered via scalar loads (readfirstlane-uniform node ->
// s_load_dwordx16 -> v_fmac with SGPR src0), not LDS/VMEM per-lane loads.

__global__ __attribute__((amdgpu_flat_work_group_size(BLOCK, BLOCK),
                          amdgpu_waves_per_eu(5)))
void tree_mlp_kernel(
    const float* __restrict__ x,
    const float* __restrict__ W1, const float* __restrict__ b1,
    const float* __restrict__ W2, const float* __restrict__ b2,
    const float* __restrict__ W3, const float* __restrict__ b3,
    const float* __restrict__ leaf_best, const int* __restrict__ subset_idx,
    float* __restrict__ out, int N)
{
    __shared__ int      subL[NNODES * NK];     // 960 B
    __shared__ unsigned permL[BLOCK];          // 2560 B
    __shared__ int      sortL[NWAVES * 8];     // 320 B (max nb = 8)

    const int tid  = threadIdx.x;
    const int lane = tid & 63;
    const int wv   = tid >> 6;

    for (int i = tid; i < NNODES * NK; i += BLOCK) subL[i] = subset_idx[i];
    __syncthreads();

    const int s = blockIdx.x * BLOCK + tid;
    int valid = (s < N) ? 1 : 0;
    int id    = valid ? s : 0;      // invalid lanes shadow sample 0 (stay live for ballots)
    int loc = 0, off = 0;

    #pragma unroll 1   // keep level loop rolled (I$)
    for (int level = 0; level < 4; ++level) {
        if (level > 0) {
            // ---- in-block counting sort by loc (nb buckets), ballot-based ----
            const int nb = 1 << level;
            int myrank = 0;
            #pragma unroll 1
            for (int b = 0; b < nb; ++b) {
                const unsigned long long m = __ballot(loc == b);
                if (loc == b)
                    myrank = __popcll(m & ((1ull << lane) - 1ull));
                if (lane == 0)
                    sortL[b * NWAVES + wv] = __popcll(m);
            }
            __syncthreads();
            if (tid == 0) {            // exclusive prefix over (bucket, wave)
                int run = 0;
                for (int i = 0; i < nb * NWAVES; ++i) {
                    const int c = sortL[i];
                    sortL[i] = run;
                    run += c;
                }
            }
            __syncthreads();
            const int slot = sortL[loc * NWAVES + wv] + myrank;
            permL[slot] = ((unsigned)id << 5) | ((unsigned)valid << 4) | (unsigned)loc;
            __syncthreads();
            const unsigned p = permL[tid];
            id    = (int)(p >> 5);
            valid = (int)((p >> 4) & 1u);
            loc   = (int)(p & 15u);
            __syncthreads();           // protect permL/sortL reuse next level
        }

        const int node = off + loc;    // sorted ascending across the wave
        const float* xr = x + (size_t)id * NF;

        // Per-lane subset gather, once per level (correct for each lane's OWN node).
        float xs[NK];
        const int* si = subL + node * NK;
        #pragma unroll
        for (int k = 0; k < NK; ++k) xs[k] = xr[si[k]];

        int bit = 0;
        const int nd0 = __builtin_amdgcn_readfirstlane(node);
        const int nd1 = __builtin_amdgcn_readlane(node, 63);

        // Loop over the distinct (consecutive) nodes present in this wave.
        // Usually 1 pass; boundary waves 2; all weights scalar-uniform per pass.
        #pragma unroll 1
        for (int nd = nd0; nd <= nd1; ++nd) {
            if (!__any(node == nd)) continue;

            const float* w1  = W1 + nd * (NH * NK);
            const float* bb1 = b1 + nd * NH;
            const float* w2  = W2 + nd * (NH * NH);
            const float* bb2 = b2 + nd * NH;
            const float* w3  = W3 + nd * (2 * NH);
            const float* bb3 = b3 + nd * 2;

            // h1 = leaky(W1 @ xs + b1)      (32x16, weights in SGPRs)
            float h1v[NH];
            #pragma unroll
            for (int j = 0; j < NH; ++j) {
                float acc = bb1[j];
                #pragma unroll
                for (int k = 0; k < NK; ++k) acc += w1[j * NK + k] * xs[k];
                h1v[j] = (acc >= 0.f) ? acc : 0.01f * acc;
            }

            // h2 = leaky(W2 @ h1 + b2)      (32x32, weights in SGPRs)
            float h2v[NH];
            #pragma unroll
            for (int g = 0; g < NH; ++g) {
                float acc = bb2[g];
                #pragma unroll
                for (int k = 0; k < NH; ++k) acc += w2[g * NH + k] * h1v[k];
                h2v[g] = (acc >= 0.f) ? acc : 0.01f * acc;
            }

            // logits; p0 < 0.5  <=>  l0 < l1 (softmax is monotone)
            float l0 = bb3[0];
            float l1 = bb3[1];
            #pragma unroll
            for (int k = 0; k < NH; ++k) l0 += w3[k] * h2v[k];
            #pragma unroll
            for (int k = 0; k < NH; ++k) l1 += w3[NH + k] * h2v[k];

            if (node == nd) bit = (l0 < l1) ? 1 : 0;
        }

        loc = 2 * loc + bit;
        off = 2 * off + 1;   // node offsets: 0, 1, 3, 7
    }

    if (valid) out[id] = leaf_best[loc];
}

extern "C" void kernel_launch(void* const* d_in, const int* in_sizes, int n_in,
                              void* d_out, int out_size, void* d_ws, size_t ws_size,
                              hipStream_t stream) {
    const float* x         = (const float*)d_in[0];
    const float* W1        = (const float*)d_in[1];
    const float* b1        = (const float*)d_in[2];
    const float* W2        = (const float*)d_in[3];
    const float* b2        = (const float*)d_in[4];
    const float* W3        = (const float*)d_in[5];
    const float* b3        = (const float*)d_in[6];
    const float* leaf_best = (const float*)d_in[7];
    const int*   subset    = (const int*)d_in[8];

    const int N = in_sizes[0] / NF;
    const int grid = (N + BLOCK - 1) / BLOCK;
    tree_mlp_kernel<<<grid, BLOCK, 0, stream>>>(
        x, W1, b1, W2, b2, W3, b3, leaf_best, subset, (float*)d_out, N);
}